// Round 17
// baseline (215.461 us; speedup 1.0000x reference)
//
#include <hip/hip_runtime.h>
#include <stdint.h>

#define PRIME 2013265921u
#define LOGN  20
#define NN    (1u << LOGN)

static constexpr uint64_t cpowmod(uint64_t b, uint64_t e){
  uint64_t r = 1; b %= PRIME;
  while (e){ if (e & 1) r = r * b % PRIME; b = b * b % PRIME; e >>= 1; }
  return r;
}
static constexpr uint32_t WFWD = (uint32_t)cpowmod(31u, (PRIME - 1u) >> LOGN);
static constexpr uint32_t WINV = (uint32_t)cpowmod(WFWD, PRIME - 2u);
static constexpr uint32_t NINV = (uint32_t)cpowmod(NN, PRIME - 2u);
static constexpr uint64_t MBAR = 0xFFFFFFFFFFFFFFFFull / PRIME;

// ---- bookkeeping in module globals; d_ws only used for the INTT mid buffer ----
__device__ uint32_t g_U[1024];            // WINV^i           (ratio + fallback, Barrett)
__device__ uint32_t g_V[1024];            // WINV^(1024 i)    (ratio + fallback, Barrett)
__device__ uint2    g_TWp[1024];          // stage-major butterfly twiddles {w, shoup}
__device__ uint2    g_U2p[1024];          // {NINV*WINV^i, shoup} pass-1 inter-twiddle
__device__ uint32_t g_bcnt[2048];
__device__ uint32_t g_boff[2048];
__device__ uint32_t g_bcur[2048];
__device__ uint32_t g_btot[2048];
__device__ uint32_t g_bpre[2048];
__device__ unsigned long long g_commit[10];

__device__ __forceinline__ uint32_t mulmod(uint32_t a, uint32_t b){
  uint64_t t = (uint64_t)a * b;
  uint32_t q = (uint32_t)__umul64hi(t, MBAR);
  uint32_t r = (uint32_t)t - q * PRIME;
  if (r >= PRIME) r -= PRIME;
  return r;
}
// Shoup: ws = floor(w * 2^32 / P); requires w < P. Result < P.
__device__ __forceinline__ uint32_t shoup_mul(uint32_t a, uint32_t w, uint32_t ws){
  uint32_t q = __umulhi(a, ws);
  uint32_t r = a * w - q * PRIME;        // mod 2^32, true value < 2P
  if (r >= PRIME) r -= PRIME;
  return r;
}
__device__ __forceinline__ uint32_t addmod(uint32_t a, uint32_t b){
  uint32_t s = a + b; return (s >= PRIME) ? s - PRIME : s;
}
__device__ __forceinline__ uint32_t submod(uint32_t a, uint32_t b){
  return (a >= b) ? (a - b) : (a + (PRIME - b));
}
__device__ __forceinline__ uint32_t addmod3(uint32_t a, uint32_t b, uint32_t c){
  return addmod(addmod(a, b), c);
}
__device__ __forceinline__ uint32_t powmod_dev(uint32_t b, uint32_t e){
  uint32_t r = 1u;
  while (e){ if (e & 1u) r = mulmod(r, b); b = mulmod(b, b); e >>= 1u; }
  return r;
}

__global__ __launch_bounds__(1024) void k_zero(){
  const uint32_t t = blockIdx.x * 1024u + threadIdx.x;
  if (t < 2048u) g_bcnt[t] = 0u;
  if (t < 10u)   g_commit[t] = 0ull;
}

__global__ __launch_bounds__(1024) void k_tables(){
  const uint32_t i = threadIdx.x;
  if (blockIdx.x == 0){
    g_U[i] = powmod_dev(WINV, i);
  } else if (blockIdx.x == 1){
    g_V[i] = powmod_dev(WINV, i << 10);
  } else if (blockIdx.x == 2){
    const uint32_t w = mulmod(NINV, powmod_dev(WINV, i));
    g_U2p[i] = make_uint2(w, (uint32_t)((((uint64_t)w) << 32) / PRIME));
  } else {
    // stage-major twiddle layout; entry i holds V[j] = WINV^(1024 j)
    uint32_t j;
    if      (i < 512u)  j = i;                     // st9 (natural order V[0..511])
    else if (i < 768u)  j = (i - 512u)  << 1;      // st8
    else if (i < 896u)  j = (i - 768u)  << 2;      // st7
    else if (i < 960u)  j = (i - 896u)  << 3;      // st6
    else if (i < 992u)  j = (i - 960u)  << 4;      // st5
    else if (i < 1008u) j = (i - 992u)  << 5;      // st4
    else if (i < 1016u) j = (i - 1008u) << 6;      // st3
    else if (i < 1020u) j = (i - 1016u) << 7;      // st2
    else if (i < 1022u) j = (i - 1020u) << 8;      // st1
    else                j = 0u;                    // st0 (w=1) + pad
    const uint32_t w = powmod_dev(WINV, j << 10);
    g_TWp[i] = make_uint2(w, (uint32_t)((((uint64_t)w) << 32) / PRIME));
  }
}

// ---------------- elementwise: t, f + bucket count ----------------
__global__ __launch_bounds__(1024) void k_elemA(
    const uint32_t* __restrict__ wl, const uint32_t* __restrict__ wr,
    const uint32_t* __restrict__ wo, const uint32_t* __restrict__ w4,
    const uint32_t* __restrict__ ql, const uint32_t* __restrict__ x1,
    const uint32_t* __restrict__ x2, const uint32_t* __restrict__ x3,
    const uint32_t* __restrict__ x4, const uint32_t* __restrict__ zeta_p,
    uint32_t* __restrict__ o32)
{
  __shared__ uint32_t hcnt[2048];
  const int t = threadIdx.x;
  hcnt[t] = 0u; hcnt[t + 1024] = 0u;
  __syncthreads();

  const uint32_t zeta = zeta_p[0];
  const uint32_t zc2 = mulmod(zeta, zeta), zc3 = mulmod(zc2, zeta);
  const uint32_t i0 = (uint32_t)blockIdx.x * 4096u + (uint32_t)t * 4u;

  uint4 vt1 = *(const uint4*)(x1 + i0);
  uint4 vt2 = *(const uint4*)(x2 + i0);
  uint4 vt3 = *(const uint4*)(x3 + i0);
  uint4 vt4 = *(const uint4*)(x4 + i0);
  uint4 vwl = *(const uint4*)(wl + i0);
  uint4 vwr = *(const uint4*)(wr + i0);
  uint4 vwo = *(const uint4*)(wo + i0);
  uint4 vw4 = *(const uint4*)(w4 + i0);
  uint4 vql = *(const uint4*)(ql + i0);

  uint32_t T1[4] = {vt1.x, vt1.y, vt1.z, vt1.w};
  uint32_t T2[4] = {vt2.x, vt2.y, vt2.z, vt2.w};
  uint32_t T3[4] = {vt3.x, vt3.y, vt3.z, vt3.w};
  uint32_t T4[4] = {vt4.x, vt4.y, vt4.z, vt4.w};
  uint32_t L1[4] = {vwl.x, vwl.y, vwl.z, vwl.w};
  uint32_t L2[4] = {vwr.x, vwr.y, vwr.z, vwr.w};
  uint32_t L3[4] = {vwo.x, vwo.y, vwo.z, vwo.w};
  uint32_t L4[4] = {vw4.x, vw4.y, vw4.z, vw4.w};
  uint32_t QL[4] = {vql.x, vql.y, vql.z, vql.w};

  uint32_t tv[4], fv[4];
  #pragma unroll
  for (int k = 0; k < 4; ++k){
    uint32_t tt = addmod(addmod(T1[k], mulmod(zeta, T2[k])),
                         addmod(mulmod(zc2, T3[k]), mulmod(zc3, T4[k])));
    uint32_t qq = addmod(addmod(L1[k], mulmod(zeta, L2[k])),
                         addmod(mulmod(zc2, L3[k]), mulmod(zc3, L4[k])));
    tv[k] = tt; fv[k] = (QL[k] == 1u) ? qq : tt;
  }
  uint4 o;
  o.x = tv[0]; o.y = tv[1]; o.z = tv[2]; o.w = tv[3];
  *(uint4*)(o32 + 5u*NN + i0) = o;                      // T -> slot5
  o.x = fv[0]; o.y = fv[1]; o.z = fv[2]; o.w = fv[3];
  *(uint4*)(o32 + 4u*NN + i0) = o;                      // F -> slot4

  #pragma unroll
  for (int k = 0; k < 4; ++k){ atomicAdd(&hcnt[fv[k] >> 20], 1u);
                               atomicAdd(&hcnt[tv[k] >> 20], 1u); }
  __syncthreads();
  uint32_t c0 = hcnt[t];          if (c0) atomicAdd(&g_bcnt[t], c0);
  uint32_t c1 = hcnt[t + 1024];   if (c1) atomicAdd(&g_bcnt[t + 1024], c1);
}

// ---------------- bucket offset scan (1 block) ----------------
__global__ __launch_bounds__(1024) void k_bscan(){
  __shared__ uint32_t SA[2048], SB[2048];
  const int t = threadIdx.x;
  SA[t] = g_bcnt[t];
  SA[t + 1024] = g_bcnt[t + 1024];
  __syncthreads();
  uint32_t* sp = SA; uint32_t* dp = SB;
  for (int off = 1; off < 2048; off <<= 1){
    for (int i = t; i < 2048; i += 1024)
      dp[i] = (i >= off) ? (sp[i - off] + sp[i]) : sp[i];
    uint32_t* tmp = sp; sp = dp; dp = tmp;
    __syncthreads();
  }
  uint32_t e0 = t ? sp[t - 1] : 0u;
  uint32_t e1 = sp[t + 1023];
  g_boff[t] = e0;         g_bcur[t] = e0;
  g_boff[t + 1024] = e1;  g_bcur[t + 1024] = e1;
}

// ---------------- aggregated scatter: block-local counting sort, then
// coalesced-run write-out into final sorted-array position ----------------
__global__ __launch_bounds__(1024) void k_scat2(uint32_t* __restrict__ o32){
  __shared__ uint32_t sorted[8192];
  __shared__ uint32_t hist[2048];
  __shared__ uint32_t SA[2048];
  __shared__ uint32_t wsum[16];
  __shared__ uint32_t gbase[2048];
  const int t = threadIdx.x;
  const uint32_t base = blockIdx.x * 8192u;   // over F|T = o32[4N .. 6N)

  hist[t] = 0u; hist[t + 1024] = 0u;
  __syncthreads();

  uint32_t v[8], rk[8];
  #pragma unroll
  for (int k = 0; k < 8; ++k)
    v[k] = o32[4u*NN + base + (uint32_t)t + (uint32_t)k * 1024u];
  #pragma unroll
  for (int k = 0; k < 8; ++k)
    rk[k] = atomicAdd(&hist[v[k] >> 20], 1u);
  __syncthreads();

  // shfl-based inclusive scan of hist[0..2047] into SA
  const uint32_t lane = (uint32_t)t & 63u, wid = (uint32_t)t >> 6;   // 16 waves
  const uint32_t e0 = hist[2*t], e1 = hist[2*t + 1];
  const uint32_t s = e0 + e1;
  uint32_t scan = s;
  #pragma unroll
  for (int off = 1; off < 64; off <<= 1){
    uint32_t u = __shfl_up(scan, off, 64);
    if (lane >= (uint32_t)off) scan += u;
  }
  if (lane == 63u) wsum[wid] = scan;
  __syncthreads();
  if (t < 64){
    uint32_t u = (t < 16) ? wsum[t] : 0u;
    #pragma unroll
    for (int off = 1; off < 16; off <<= 1){
      uint32_t x2 = __shfl_up(u, off, 64);
      if ((uint32_t)t >= (uint32_t)off) u += x2;
    }
    if (t < 16) wsum[t] = u;
  }
  __syncthreads();
  const uint32_t wbase = wid ? wsum[wid - 1] : 0u;
  const uint32_t incl = wbase + scan;
  SA[2*t]     = incl - e1;
  SA[2*t + 1] = incl;
  __syncthreads();
  uint32_t* sp = SA;

  // reserve global space: one atomic per non-empty bucket per block
  for (int b = t; b < 2048; b += 1024){
    uint32_t c = hist[b];
    if (c) gbase[b] = atomicAdd(&g_bcur[b], c);
  }
  __syncthreads();

  // scatter into bucket-sorted LDS order
  #pragma unroll
  for (int k = 0; k < 8; ++k){
    uint32_t b = v[k] >> 20;
    uint32_t ls = b ? sp[b - 1] : 0u;
    sorted[ls + rk[k]] = v[k];
  }
  __syncthreads();

  // linear write-out: consecutive i in same bucket -> consecutive global dst
  for (int i = t; i < 8192; i += 1024){
    uint32_t vv = sorted[i];
    uint32_t b = vv >> 20;
    uint32_t ls = b ? sp[b - 1] : 0u;
    o32[6u*NN + gbase[b] + (uint32_t)i - ls] = vv;
  }
}

// ---------------- per-bucket sort: MSD digit (bits [10,20)) counting sort
// + tiny per-digit insertion sort. Values in a bucket share the top 11 bits. --
__global__ __launch_bounds__(256) void k_bsort(uint32_t* __restrict__ o32){
  __shared__ uint32_t sorted[2048];
  __shared__ uint32_t SA[1024], SB[1024];
  __shared__ uint32_t wsum[4];
  const int b = blockIdx.x, t = threadIdx.x;
  uint32_t n = g_bcnt[b]; if (n > 2048u) n = 2048u;
  const uint32_t off = g_boff[b];

  for (int i = t; i < 1024; i += 256) SA[i] = 0u;
  __syncthreads();

  uint32_t v[8], rk[8];
  #pragma unroll
  for (int k = 0; k < 8; ++k){
    const uint32_t i = (uint32_t)t + (uint32_t)k * 256u;
    if (i < n){
      v[k] = o32[6u*NN + off + i];
      rk[k] = atomicAdd(&SA[(v[k] >> 10) & 1023u], 1u);
    }
  }
  __syncthreads();

  // shfl-based inclusive scan of SA[0..1023] into SB
  const uint32_t lane = (uint32_t)t & 63u, wid = (uint32_t)t >> 6;   // 4 waves
  const uint32_t h0 = SA[4*t], h1 = SA[4*t + 1], h2 = SA[4*t + 2], h3 = SA[4*t + 3];
  const uint32_t s = h0 + h1 + h2 + h3;
  uint32_t scan = s;
  #pragma unroll
  for (int o = 1; o < 64; o <<= 1){
    uint32_t u = __shfl_up(scan, o, 64);
    if (lane >= (uint32_t)o) scan += u;
  }
  if (lane == 63u) wsum[wid] = scan;
  __syncthreads();
  if (t < 64){
    uint32_t u = (t < 4) ? wsum[t] : 0u;
    #pragma unroll
    for (int o = 1; o < 4; o <<= 1){
      uint32_t x2 = __shfl_up(u, o, 64);
      if ((uint32_t)t >= (uint32_t)o) u += x2;
    }
    if (t < 4) wsum[t] = u;
  }
  __syncthreads();
  const uint32_t wbase = wid ? wsum[wid - 1] : 0u;
  const uint32_t incl = wbase + scan;
  SB[4*t + 3] = incl;
  SB[4*t + 2] = incl - h3;
  SB[4*t + 1] = incl - h3 - h2;
  SB[4*t + 0] = incl - h3 - h2 - h1;
  __syncthreads();
  uint32_t* sp = SB;

  // scatter by digit
  #pragma unroll
  for (int k = 0; k < 8; ++k){
    const uint32_t i = (uint32_t)t + (uint32_t)k * 256u;
    if (i < n){
      const uint32_t d = (v[k] >> 10) & 1023u;
      const uint32_t s2 = d ? sp[d - 1] : 0u;
      sorted[s2 + rk[k]] = v[k];
    }
  }
  __syncthreads();

  // finish each digit run (mean length <= 2, max ~12) with insertion sort
  for (int d = t; d < 1024; d += 256){
    const uint32_t s2 = d ? sp[d - 1] : 0u;
    const uint32_t e = sp[d];
    for (uint32_t i = s2 + 1; i < e; ++i){
      const uint32_t key = sorted[i];
      uint32_t j = i;
      while (j > s2 && sorted[j - 1] > key){ sorted[j] = sorted[j - 1]; --j; }
      sorted[j] = key;
    }
  }
  __syncthreads();

  for (uint32_t i = (uint32_t)t; i < n; i += 256u) o32[6u*NN + off + i] = sorted[i];
}

// ---------------- ratios + block-local multiplicative scan (8 elems/thread) --
__global__ __launch_bounds__(256) void k_ratio(
    const uint32_t* __restrict__ wl, const uint32_t* __restrict__ wr,
    const uint32_t* __restrict__ wo, const uint32_t* __restrict__ w4,
    const uint32_t* __restrict__ sl, const uint32_t* __restrict__ sr,
    const uint32_t* __restrict__ so, const uint32_t* __restrict__ s4,
    const uint32_t* __restrict__ beta_p, const uint32_t* __restrict__ gamma_p,
    const uint32_t* __restrict__ delta_p, const uint32_t* __restrict__ eps_p,
    uint32_t* __restrict__ o32)
{
  __shared__ uint32_t SA[256], SB[256];
  const int blk = blockIdx.x, t = threadIdx.x;         // 1024 blocks: 512 z | 512 z2
  const int second = blk >> 9;
  const uint32_t base = ((uint32_t)(blk & 511) << 11) + ((uint32_t)t << 3);
  uint32_t num[8], den[8];
  if (!second){
    const uint32_t beta = beta_p[0], gamma = gamma_p[0];
    #pragma unroll
    for (int k = 0; k < 8; ++k){
      uint32_t i = base + (uint32_t)k;
      uint32_t e = (NN - i) & (NN - 1u);               // W^i = WINV^((N-i) mod N)
      uint32_t om = mulmod(g_U[e & 1023u], g_V[e >> 10]);
      uint32_t bo = mulmod(beta, om);
      uint32_t n = addmod3(wl[i], bo, gamma);
      n = mulmod(n, addmod3(wr[i], mulmod(7u,  bo), gamma));
      n = mulmod(n, addmod3(wo[i], mulmod(13u, bo), gamma));
      n = mulmod(n, addmod3(w4[i], mulmod(17u, bo), gamma));
      uint32_t d = addmod3(wl[i], mulmod(beta, sl[i]), gamma);
      d = mulmod(d, addmod3(wr[i], mulmod(beta, sr[i]), gamma));
      d = mulmod(d, addmod3(wo[i], mulmod(beta, so[i]), gamma));
      d = mulmod(d, addmod3(w4[i], mulmod(beta, s4[i]), gamma));
      num[k] = n; den[k] = d;
    }
  } else {
    const uint32_t del = delta_p[0], ep = eps_p[0];
    const uint32_t opd = addmod(1u, del), ep1d = mulmod(ep, opd);
    #pragma unroll
    for (int k = 0; k < 8; ++k){
      uint32_t i = base + (uint32_t)k;
      uint32_t fi = o32[4u*NN + i], ti = o32[5u*NN + i];
      uint32_t tn = o32[5u*NN + ((i + 1u) & (NN - 1u))];
      uint32_t h1  = o32[6u*NN + 2u*i];
      uint32_t h2  = o32[6u*NN + 2u*i + 1u];
      uint32_t h1n = o32[6u*NN + ((2u*i + 2u) & (2u*NN - 1u))];
      uint32_t h2n = o32[6u*NN + ((2u*i + 3u) & (2u*NN - 1u))];
      uint32_t n = mulmod(opd, addmod(ep, fi));
      n = mulmod(n, addmod3(ep1d, ti, mulmod(del, tn)));
      uint32_t d = mulmod(addmod3(ep1d, h1, mulmod(del, h1n)),
                          addmod3(ep1d, h2, mulmod(del, h2n)));
      num[k] = n; den[k] = d;
    }
  }
  bool ok = true;
  #pragma unroll
  for (int k = 0; k < 8; ++k) ok = ok && (den[k] != 0u);
  uint32_t r[8];
  if (ok){
    uint32_t pp[8];
    pp[0] = den[0];
    #pragma unroll
    for (int k = 1; k < 8; ++k) pp[k] = mulmod(pp[k-1], den[k]);
    uint32_t iv = powmod_dev(pp[7], PRIME - 2u);
    #pragma unroll
    for (int k = 7; k >= 1; --k){
      r[k] = mulmod(num[k], mulmod(iv, pp[k-1]));
      iv = mulmod(iv, den[k]);
    }
    r[0] = mulmod(num[0], iv);
  } else {
    #pragma unroll
    for (int k = 0; k < 8; ++k) r[k] = mulmod(num[k], powmod_dev(den[k], PRIME - 2u));
  }
  uint32_t tp = r[0];
  #pragma unroll
  for (int k = 1; k < 8; ++k) tp = mulmod(tp, r[k]);
  SA[t] = tp; __syncthreads();
  uint32_t* sp = SA; uint32_t* dp = SB;
  for (int off = 1; off < 256; off <<= 1){
    dp[t] = (t >= off) ? mulmod(sp[t - off], sp[t]) : sp[t];
    uint32_t* tmp = sp; sp = dp; dp = tmp;
    __syncthreads();
  }
  if (t == 255) g_btot[blk] = sp[255];
  uint32_t run = t ? sp[t - 1] : 1u;
  const uint32_t zo = 8u*NN + ((uint32_t)second << 20) + base;
  #pragma unroll
  for (int k = 0; k < 8; ++k){
    o32[zo + (uint32_t)k] = run;
    run = mulmod(run, r[k]);
  }
}

__global__ __launch_bounds__(512) void k_btscan(){
  __shared__ uint32_t SA[512], SB[512];
  const int a = blockIdx.x, t = threadIdx.x;
  SA[t] = g_btot[a * 512 + t];
  __syncthreads();
  uint32_t* sp = SA; uint32_t* dp = SB;
  for (int off = 1; off < 512; off <<= 1){
    dp[t] = (t >= off) ? mulmod(sp[t - off], sp[t]) : sp[t];
    uint32_t* tmp = sp; sp = dp; dp = tmp;
    __syncthreads();
  }
  g_bpre[a * 512 + t] = t ? sp[t - 1] : 1u;
}

__global__ __launch_bounds__(256) void k_apply(uint32_t* __restrict__ o32){
  const uint32_t g = blockIdx.x * 256u + threadIdx.x;   // [0, 2N/4)
  const uint32_t base = g << 2;
  const uint32_t m = g_bpre[base >> 11];
  uint4* zz = (uint4*)(o32 + 8u*NN);
  uint4 v = zz[g];
  v.x = mulmod(v.x, m); v.y = mulmod(v.y, m); v.z = mulmod(v.z, m); v.w = mulmod(v.w, m);
  zz[g] = v;
}

// ================= four-step INTT: 512-thr blocks, 2 columns/wave, 32KB half-staging
//                   (16-col tiles keep 64B row loads; 40KB LDS -> 4 blocks/CU,
//                    all 640 blocks resident -> no dispatch tail) =================
struct Desc  { const uint32_t* p; uint32_t stride; uint32_t off; };
struct Descs { Desc d[10]; };
struct Map   { int g[10]; };

#define SWZ(i, c) (((i) << 4) + ((c) ^ (((i) >> 1) & 15)))

// Dual-column 1024-pt GS-DIF NTT on registers: lane l, reg r hold position
// p = l + 64r of columns A and B. Twiddle LDS reads shared across A/B.
// On exit position p holds X[rev10(p)].
__device__ __forceinline__ void ntt1024_reg2(uint32_t xA[16], uint32_t xB[16], int l,
                                             const uint2* __restrict__ sTW){
  #pragma unroll
  for (int st = 9; st >= 6; --st){
    const int bb = 1 << (st - 6);
    const int base = (st == 9) ? 0 : (st == 8) ? 512 : (st == 7) ? 768 : 896;
    #pragma unroll
    for (int r = 0; r < 16; ++r){
      if ((r & bb) == 0){
        const int r2 = r | bb;
        const uint2 wv = sTW[base + ((r & (bb - 1)) << 6) + l];
        const uint32_t uA = xA[r], vA = xA[r2];
        xA[r]  = addmod(uA, vA);
        xA[r2] = shoup_mul(submod(uA, vA), wv.x, wv.y);
        const uint32_t uB = xB[r], vB = xB[r2];
        xB[r]  = addmod(uB, vB);
        xB[r2] = shoup_mul(submod(uB, vB), wv.x, wv.y);
      }
    }
  }
  #pragma unroll
  for (int st = 5; st >= 0; --st){
    const int h = 1 << st;
    const int base = (st == 5) ? 960 : (st == 4) ? 992 : (st == 3) ? 1008
                   : (st == 2) ? 1016 : (st == 1) ? 1020 : 1022;
    const uint2 wv = sTW[base + (l & (h - 1))];
    const bool hi = (l & h) != 0;
    #pragma unroll
    for (int r = 0; r < 16; ++r){
      const uint32_t yA = __shfl_xor(xA[r], h, 64);
      const uint32_t aA = addmod(xA[r], yA);
      const uint32_t bA = shoup_mul(submod(yA, xA[r]), wv.x, wv.y);
      xA[r] = hi ? bA : aA;
      const uint32_t yB = __shfl_xor(xB[r], h, 64);
      const uint32_t aB = addmod(xB[r], yB);
      const uint32_t bB = shoup_mul(submod(yB, xB[r]), wv.x, wv.y);
      xB[r] = hi ? bB : aB;
    }
  }
}

__global__ __launch_bounds__(512, 8) void k_intt1(Descs ds, uint32_t* __restrict__ mid){
  __shared__ uint32_t tile[8192];          // 32KB: 512 rows x 16 cols (one half)
  __shared__ uint2 sTW[1024];
  const int t = threadIdx.x;
  sTW[t] = g_TWp[t];
  sTW[t + 512] = g_TWp[t + 512];
  const int arr = blockIdx.x >> 6;
  const int c0 = (blockIdx.x & 63) << 4;
  const Desc de = ds.d[arr];
  const int w = t >> 6, l = t & 63;        // w in [0,8): wave owns cols c0+w, c0+w+8
  uint32_t xA[16], xB[16];

  #pragma unroll
  for (int H = 0; H < 2; ++H){
    if (H) __syncthreads();                // previous half's reg reads complete
    if (de.stride == 1u){
      #pragma unroll
      for (int it = 0; it < 4; ++it){
        const int rl = (it << 7) + (t >> 2);          // [0,512)
        const int cb = (t & 3) << 2;
        const int row = (H << 9) + rl;
        uint4 v = *(const uint4*)(de.p + (size_t)row * 1024u + (uint32_t)(c0 + cb));
        tile[SWZ(rl, cb + 0)] = v.x; tile[SWZ(rl, cb + 1)] = v.y;
        tile[SWZ(rl, cb + 2)] = v.z; tile[SWZ(rl, cb + 3)] = v.w;
      }
    } else {                               // stride 2 (h1/h2 from S)
      #pragma unroll
      for (int it = 0; it < 4; ++it){
        const int rl = (it << 7) + (t >> 2);
        const int cb = (t & 3) << 2;
        const int row = (H << 9) + rl;
        const size_t b0 = 2u * ((size_t)row * 1024u + (uint32_t)(c0 + cb));
        uint4 a0 = *(const uint4*)(de.p + b0);
        uint4 a1 = *(const uint4*)(de.p + b0 + 4u);
        if (de.off == 0u){
          tile[SWZ(rl, cb + 0)] = a0.x; tile[SWZ(rl, cb + 1)] = a0.z;
          tile[SWZ(rl, cb + 2)] = a1.x; tile[SWZ(rl, cb + 3)] = a1.z;
        } else {
          tile[SWZ(rl, cb + 0)] = a0.y; tile[SWZ(rl, cb + 1)] = a0.w;
          tile[SWZ(rl, cb + 2)] = a1.y; tile[SWZ(rl, cb + 3)] = a1.w;
        }
      }
    }
    __syncthreads();
    #pragma unroll
    for (int r = 0; r < 8; ++r){
      const int rl = l + (r << 6);         // position p = rl + 512H
      xA[(H << 3) + r] = tile[SWZ(rl, w)];
      xB[(H << 3) + r] = tile[SWZ(rl, w + 8)];
    }
  }
  ntt1024_reg2(xA, xB, l, sTW);
  // inter-pass twiddle (N^-1 folded into U2): position p holds X[rev10(p)].
  // U2 gathers from global (L1-resident); V[h<512] from sTW st9 region;
  // V[512+j] = P - V[j] with shoup companion ~ws (exact).
  const uint32_t i1gA = (uint32_t)(c0 + w);
  const uint32_t i1gB = (uint32_t)(c0 + w + 8);
  const uint32_t rl6 = __brev((uint32_t)l) >> 26;       // rev6(l)
  #pragma unroll
  for (int r = 0; r < 16; ++r){
    const uint32_t rr = __brev((uint32_t)r) >> 28;      // rev4(r)
    const uint32_t j1 = (rl6 << 4) | rr;
    {
      const uint32_t e = j1 * i1gA;                     // < 2^20
      const uint2 wa = g_U2p[e & 1023u];
      const uint32_t hv = e >> 10;
      const uint2 wb = sTW[hv & 511u];
      uint32_t wbw = wb.x, wbs = wb.y;
      if (hv & 512u){ wbw = PRIME - wbw; wbs = ~wbs; }
      xA[r] = shoup_mul(shoup_mul(xA[r], wa.x, wa.y), wbw, wbs);
    }
    {
      const uint32_t e = j1 * i1gB;
      const uint2 wa = g_U2p[e & 1023u];
      const uint32_t hv = e >> 10;
      const uint2 wb = sTW[hv & 511u];
      uint32_t wbw = wb.x, wbs = wb.y;
      if (hv & 512u){ wbw = PRIME - wbw; wbs = ~wbs; }
      xB[r] = shoup_mul(shoup_mul(xB[r], wa.x, wa.y), wbw, wbs);
    }
  }
  uint32_t* mo = mid + ((size_t)arr << 20);
  #pragma unroll
  for (int H = 0; H < 2; ++H){
    __syncthreads();                       // prior tile reads complete
    #pragma unroll
    for (int r = 0; r < 8; ++r){
      const int rl = l + (r << 6);
      tile[SWZ(rl, w)]     = xA[(H << 3) + r];
      tile[SWZ(rl, w + 8)] = xB[(H << 3) + r];
    }
    __syncthreads();
    #pragma unroll
    for (int it = 0; it < 4; ++it){
      const int rl = (it << 7) + (t >> 2);
      const int cb = (t & 3) << 2;
      const int row = (H << 9) + rl;
      uint4 v;
      v.x = tile[SWZ(rl, cb + 0)]; v.y = tile[SWZ(rl, cb + 1)];
      v.z = tile[SWZ(rl, cb + 2)]; v.w = tile[SWZ(rl, cb + 3)];
      *(uint4*)(mo + (size_t)row * 1024u + (uint32_t)(c0 + cb)) = v;
    }
  }
}

__global__ __launch_bounds__(512, 8) void k_intt2(const uint32_t* __restrict__ mid,
                                                  uint32_t* __restrict__ o32,
                                                  const uint32_t* __restrict__ ck,
                                                  Map mp){
  __shared__ uint32_t tile[8192];
  __shared__ uint2 sTW[1024];
  const int t = threadIdx.x;
  sTW[t] = g_TWp[t];
  sTW[t + 512] = g_TWp[t + 512];
  const int arrL = blockIdx.x >> 6;
  const int m0 = (blockIdx.x & 63) << 4;
  const int w = t >> 6, l = t & 63;
  const int gidx = mp.g[arrL];
  const uint32_t* mi = mid + ((size_t)arrL << 20);
  const uint32_t pA = __brev((uint32_t)(m0 + w)) >> 22;       // source row, col m0+w
  const uint32_t pB = __brev((uint32_t)(m0 + w + 8)) >> 22;   // source row, col m0+w+8
  uint32_t xA[16], xB[16];

  #pragma unroll
  for (int H = 0; H < 2; ++H){
    if (H) __syncthreads();
    #pragma unroll
    for (int it = 0; it < 2; ++it){
      const int kb = (it << 8) + (l << 2);              // [0,512)
      const int k2 = (H << 9) + kb;
      uint4 v = *(const uint4*)(mi + pA * 1024u + (uint32_t)k2);
      tile[SWZ(kb + 0, w)] = v.x; tile[SWZ(kb + 1, w)] = v.y;
      tile[SWZ(kb + 2, w)] = v.z; tile[SWZ(kb + 3, w)] = v.w;
      uint4 u = *(const uint4*)(mi + pB * 1024u + (uint32_t)k2);
      tile[SWZ(kb + 0, w + 8)] = u.x; tile[SWZ(kb + 1, w + 8)] = u.y;
      tile[SWZ(kb + 2, w + 8)] = u.z; tile[SWZ(kb + 3, w + 8)] = u.w;
    }
    __syncthreads();
    #pragma unroll
    for (int r = 0; r < 8; ++r){
      const int rl = l + (r << 6);
      xA[(H << 3) + r] = tile[SWZ(rl, w)];
      xB[(H << 3) + r] = tile[SWZ(rl, w + 8)];
    }
  }
  ntt1024_reg2(xA, xB, l, sTW);
  unsigned long long acc = 0ull;
  uint32_t* oa = o32 + ((size_t)gidx << 20);
  #pragma unroll
  for (int H = 0; H < 2; ++H){
    __syncthreads();                       // prior tile reads complete
    #pragma unroll
    for (int r = 0; r < 8; ++r){
      const int rl = l + (r << 6);         // position p = rl + 512H
      tile[SWZ(rl, w)]     = xA[(H << 3) + r];
      tile[SWZ(rl, w + 8)] = xB[(H << 3) + r];
    }
    __syncthreads();
    // output rows j2 = 2m + H (q = rev10(j2) lies in [512H, 512H+512))
    #pragma unroll
    for (int it = 0; it < 4; ++it){
      const int m = (it << 7) + (t >> 2);               // [0,512)
      const int j2 = (m << 1) | H;
      const uint32_t q = __brev((uint32_t)j2) >> 22;
      const int ql = (int)(q & 511u);
      const int rb = (t & 3) << 2;
      uint4 v;
      v.x = tile[SWZ(ql, rb + 0)]; v.y = tile[SWZ(ql, rb + 1)];
      v.z = tile[SWZ(ql, rb + 2)]; v.w = tile[SWZ(ql, rb + 3)];
      const uint32_t oi = (uint32_t)j2 * 1024u + (uint32_t)(m0 + rb);
      *(uint4*)(oa + oi) = v;                            // int32 output
      uint4 cv = *(const uint4*)(ck + oi);
      acc += (unsigned long long)mulmod(v.x, cv.x);
      acc += (unsigned long long)mulmod(v.y, cv.y);
      acc += (unsigned long long)mulmod(v.z, cv.z);
      acc += (unsigned long long)mulmod(v.w, cv.w);
    }
  }
  // wave-level reduce, then 8 wave-sums via first wave (reuse tile)
  #pragma unroll
  for (int off = 32; off >= 1; off >>= 1) acc += __shfl_down(acc, off, 64);
  __syncthreads();
  unsigned long long* redw = (unsigned long long*)tile;
  if (l == 0) redw[w] = acc;
  __syncthreads();
  if (t < 64){
    unsigned long long s = (t < 8) ? redw[t] : 0ull;
    #pragma unroll
    for (int off = 4; off >= 1; off >>= 1) s += __shfl_down(s, off, 64);
    if (t == 0) atomicAdd(&g_commit[gidx], s);
  }
}

// ================= textbook INTT (fallback when ws too small) =================
__global__ __launch_bounds__(256) void k_brev(const uint32_t* __restrict__ src,
                                              uint32_t stride, uint32_t off,
                                              uint32_t* __restrict__ dst){
  const uint32_t i = blockIdx.x * 256u + threadIdx.x;    // [0, N)
  const uint32_t r = __brev(i) >> 12;                    // bitrev20
  dst[i] = src[(size_t)r * stride + off];
}

__global__ __launch_bounds__(1024) void k_stage09(uint32_t* __restrict__ wk){
  __shared__ uint32_t sm[1024];
  const int t = threadIdx.x;
  const uint32_t gbase = blockIdx.x * 1024u;
  sm[t] = wk[gbase + t];
  __syncthreads();
  for (int s = 0; s <= 9; ++s){
    if (t < 512){
      const int half = 1 << s;
      const int k = t & (half - 1);
      const int i0 = ((t >> s) << (s + 1)) | k;
      const int i1 = i0 + half;
      const uint32_t tw = g_V[(uint32_t)k << (9 - s)];
      const uint32_t u = sm[i0];
      const uint32_t tv = mulmod(sm[i1], tw);
      sm[i0] = addmod(u, tv);
      sm[i1] = submod(u, tv);
    }
    __syncthreads();
  }
  wk[gbase + t] = sm[t];
}

__global__ __launch_bounds__(256) void k_stage(uint32_t* __restrict__ wk, int s){
  const uint32_t q = blockIdx.x * 256u + threadIdx.x;    // [0, N/2)
  const uint32_t half = 1u << s;
  const uint32_t k = q & (half - 1u);
  const uint32_t i0 = ((q >> s) << (s + 1)) | k;
  const uint32_t i1 = i0 + half;
  const uint32_t e = k << (19 - s);
  const uint32_t tw = mulmod(g_U[e & 1023u], g_V[e >> 10]);
  const uint32_t u = wk[i0];
  const uint32_t tv = mulmod(wk[i1], tw);
  wk[i0] = addmod(u, tv);
  wk[i1] = submod(u, tv);
}

__global__ __launch_bounds__(1024) void k_scale_commit(const uint32_t* __restrict__ src,
                                                       uint32_t* dst,
                                                       const uint32_t* __restrict__ ck,
                                                       int cidx){
  __shared__ unsigned long long red[1024];
  const uint32_t i = blockIdx.x * 1024u + threadIdx.x;   // [0, N)
  const uint32_t val = mulmod(src[i], NINV);
  dst[i] = val;                                          // int32 output
  red[threadIdx.x] = (unsigned long long)mulmod(val, ck[i]);
  __syncthreads();
  for (int s = 512; s > 0; s >>= 1){
    if ((int)threadIdx.x < s) red[threadIdx.x] += red[threadIdx.x + s];
    __syncthreads();
  }
  if (threadIdx.x == 0) atomicAdd(&g_commit[cidx], red[0]);
}

__global__ void k_final(uint32_t* __restrict__ out){
  const int i = threadIdx.x;
  if (i < 10) out[(size_t)10 * NN + i] = (uint32_t)(g_commit[i] % (unsigned long long)PRIME);
}

// ---------------- host ----------------
extern "C" void kernel_launch(void* const* d_in, const int* in_sizes, int n_in,
                              void* d_out, int out_size, void* d_ws, size_t ws_size,
                              hipStream_t stream)
{
  const uint32_t* wl   = (const uint32_t*)d_in[0];
  const uint32_t* wr   = (const uint32_t*)d_in[1];
  const uint32_t* wo   = (const uint32_t*)d_in[2];
  const uint32_t* w4   = (const uint32_t*)d_in[3];
  const uint32_t* ql   = (const uint32_t*)d_in[4];
  const uint32_t* t1   = (const uint32_t*)d_in[5];
  const uint32_t* t2   = (const uint32_t*)d_in[6];
  const uint32_t* t3   = (const uint32_t*)d_in[7];
  const uint32_t* t4   = (const uint32_t*)d_in[8];
  const uint32_t* sl   = (const uint32_t*)d_in[9];
  const uint32_t* sr   = (const uint32_t*)d_in[10];
  const uint32_t* so   = (const uint32_t*)d_in[11];
  const uint32_t* s4   = (const uint32_t*)d_in[12];
  const uint32_t* ck   = (const uint32_t*)d_in[13];
  const uint32_t* zeta = (const uint32_t*)d_in[14];
  const uint32_t* beta = (const uint32_t*)d_in[15];
  const uint32_t* gam  = (const uint32_t*)d_in[16];
  const uint32_t* del  = (const uint32_t*)d_in[17];
  const uint32_t* eps  = (const uint32_t*)d_in[18];
  uint32_t* o32 = (uint32_t*)d_out;
  (void)in_sizes; (void)n_in; (void)out_size;

  k_zero  <<<2, 1024, 0, stream>>>();
  k_tables<<<4, 1024, 0, stream>>>();
  k_elemA <<<256, 1024, 0, stream>>>(wl, wr, wo, w4, ql, t1, t2, t3, t4, zeta, o32);
  k_bscan <<<1, 1024, 0, stream>>>();
  k_scat2 <<<256, 1024, 0, stream>>>(o32);
  k_bsort <<<1920, 256, 0, stream>>>(o32);
  k_ratio <<<1024, 256, 0, stream>>>(wl, wr, wo, w4, sl, sr, so, s4, beta, gam, del, eps, o32);
  k_btscan<<<2, 512, 0, stream>>>();
  k_apply <<<2048, 256, 0, stream>>>(o32);

  // unified source descriptors, indexed by output slot
  Desc ds[10];
  ds[0] = { wl,          1u, 0u };
  ds[1] = { wr,          1u, 0u };
  ds[2] = { wo,          1u, 0u };
  ds[3] = { w4,          1u, 0u };
  ds[4] = { o32 + 4u*NN, 1u, 0u };   // f
  ds[5] = { o32 + 5u*NN, 1u, 0u };   // t
  ds[6] = { o32 + 6u*NN, 2u, 0u };   // h1 = S[0::2]
  ds[7] = { o32 + 6u*NN, 2u, 1u };   // h2 = S[1::2]
  ds[8] = { o32 + 8u*NN, 1u, 0u };   // z
  ds[9] = { o32 + 9u*NN, 1u, 0u };   // z2

  const size_t wsWords = ws_size / 4u;
  if (wsWords >= 2ull * NN){
    // four-step fast path; h1,h2 must share a chunk (their dsts overwrite S)
    static const int ord[10] = {6,7, 4,5, 8,9, 0,1, 2,3};
    const int chunk = (wsWords >= 10ull * NN) ? 10 : 2;
    uint32_t* mid = (uint32_t*)d_ws;
    for (int s0 = 0; s0 < 10; s0 += chunk){
      const int cnt = (10 - s0 < chunk) ? (10 - s0) : chunk;
      Descs sub; Map mp;
      for (int a = 0; a < 10; ++a){
        const int g = ord[(a < cnt) ? s0 + a : s0];
        sub.d[a] = ds[g]; mp.g[a] = g;
      }
      k_intt1<<<64 * cnt, 512, 0, stream>>>(sub, mid);
      k_intt2<<<64 * cnt, 512, 0, stream>>>(mid, o32, ck, mp);
    }
  } else {
    // textbook fallback entirely inside d_out
    auto run_intt = [&](const Desc& d, uint32_t workSlot, int dstSlot){
      uint32_t* wk = o32 + (size_t)workSlot * NN;
      k_brev   <<<4096, 256, 0, stream>>>(d.p, d.stride, d.off, wk);
      k_stage09<<<1024, 1024, 0, stream>>>(wk);
      for (int s = 10; s < 20; ++s)
        k_stage<<<2048, 256, 0, stream>>>(wk, s);
      k_scale_commit<<<1024, 1024, 0, stream>>>(wk, o32 + (size_t)dstSlot * NN, ck, dstSlot);
    };
    // h1/h2: gather both from S before either output overwrites S
    k_brev<<<4096, 256, 0, stream>>>(ds[6].p, 2u, 0u, o32 + 0u*NN);
    k_brev<<<4096, 256, 0, stream>>>(ds[7].p, 2u, 1u, o32 + 1u*NN);
    {
      uint32_t* wk0 = o32;
      uint32_t* wk1 = o32 + NN;
      k_stage09<<<1024, 1024, 0, stream>>>(wk0);
      for (int s = 10; s < 20; ++s) k_stage<<<2048, 256, 0, stream>>>(wk0, s);
      k_scale_commit<<<1024, 1024, 0, stream>>>(wk0, o32 + 6u*NN, ck, 6);
      k_stage09<<<1024, 1024, 0, stream>>>(wk1);
      for (int s = 10; s < 20; ++s) k_stage<<<2048, 256, 0, stream>>>(wk1, s);
      k_scale_commit<<<1024, 1024, 0, stream>>>(wk1, o32 + 7u*NN, ck, 7);
    }
    run_intt(ds[4], 0u, 4);
    run_intt(ds[5], 1u, 5);
    run_intt(ds[8], 0u, 8);
    run_intt(ds[9], 1u, 9);
    run_intt(ds[0], 0u, 0);
    run_intt(ds[1], 1u, 1);
    run_intt(ds[2], 2u, 2);
    run_intt(ds[3], 3u, 3);
  }
  k_final<<<1, 64, 0, stream>>>(o32);
}

// Round 18
// 199.864 us; speedup vs baseline: 1.0780x; 1.0780x over previous
//
#include <hip/hip_runtime.h>
#include <stdint.h>

#define PRIME 2013265921u
#define LOGN  20
#define NN    (1u << LOGN)

static constexpr uint64_t cpowmod(uint64_t b, uint64_t e){
  uint64_t r = 1; b %= PRIME;
  while (e){ if (e & 1) r = r * b % PRIME; b = b * b % PRIME; e >>= 1; }
  return r;
}
static constexpr uint32_t WFWD = (uint32_t)cpowmod(31u, (PRIME - 1u) >> LOGN);
static constexpr uint32_t WINV = (uint32_t)cpowmod(WFWD, PRIME - 2u);
static constexpr uint32_t NINV = (uint32_t)cpowmod(NN, PRIME - 2u);
static constexpr uint64_t MBAR = 0xFFFFFFFFFFFFFFFFull / PRIME;

// ---- bookkeeping in module globals; d_ws only used for the INTT mid buffer ----
__device__ uint32_t g_U[1024];            // WINV^i           (ratio + fallback, Barrett)
__device__ uint32_t g_V[1024];            // WINV^(1024 i)    (ratio + fallback, Barrett)
__device__ uint2    g_TWp[1024];          // stage-major butterfly twiddles {w, shoup}
__device__ uint2    g_U2p[1024];          // {NINV*WINV^i, shoup} pass-1 inter-twiddle
__device__ uint32_t g_bcnt[2048];
__device__ uint32_t g_boff[2048];
__device__ uint32_t g_bcur[2048];
__device__ uint32_t g_btot[2048];
__device__ uint32_t g_bpre[2048];
__device__ unsigned long long g_commit[10];

__device__ __forceinline__ uint32_t mulmod(uint32_t a, uint32_t b){
  uint64_t t = (uint64_t)a * b;
  uint32_t q = (uint32_t)__umul64hi(t, MBAR);
  uint32_t r = (uint32_t)t - q * PRIME;
  if (r >= PRIME) r -= PRIME;
  return r;
}
// Shoup: ws = floor(w * 2^32 / P); requires w < P. Result < P.
__device__ __forceinline__ uint32_t shoup_mul(uint32_t a, uint32_t w, uint32_t ws){
  uint32_t q = __umulhi(a, ws);
  uint32_t r = a * w - q * PRIME;        // mod 2^32, true value < 2P
  if (r >= PRIME) r -= PRIME;
  return r;
}
__device__ __forceinline__ uint32_t addmod(uint32_t a, uint32_t b){
  uint32_t s = a + b; return (s >= PRIME) ? s - PRIME : s;
}
__device__ __forceinline__ uint32_t submod(uint32_t a, uint32_t b){
  return (a >= b) ? (a - b) : (a + (PRIME - b));
}
__device__ __forceinline__ uint32_t addmod3(uint32_t a, uint32_t b, uint32_t c){
  return addmod(addmod(a, b), c);
}
__device__ __forceinline__ uint32_t powmod_dev(uint32_t b, uint32_t e){
  uint32_t r = 1u;
  while (e){ if (e & 1u) r = mulmod(r, b); b = mulmod(b, b); e >>= 1u; }
  return r;
}

__global__ __launch_bounds__(1024) void k_zero(){
  const uint32_t t = blockIdx.x * 1024u + threadIdx.x;
  if (t < 2048u) g_bcnt[t] = 0u;
  if (t < 10u)   g_commit[t] = 0ull;
}

__global__ __launch_bounds__(1024) void k_tables(){
  const uint32_t i = threadIdx.x;
  if (blockIdx.x == 0){
    g_U[i] = powmod_dev(WINV, i);
  } else if (blockIdx.x == 1){
    g_V[i] = powmod_dev(WINV, i << 10);
  } else if (blockIdx.x == 2){
    const uint32_t w = mulmod(NINV, powmod_dev(WINV, i));
    g_U2p[i] = make_uint2(w, (uint32_t)((((uint64_t)w) << 32) / PRIME));
  } else {
    // stage-major twiddle layout; entry i holds V[j] = WINV^(1024 j)
    uint32_t j;
    if      (i < 512u)  j = i;                     // st9 (natural order V[0..511])
    else if (i < 768u)  j = (i - 512u)  << 1;      // st8
    else if (i < 896u)  j = (i - 768u)  << 2;      // st7
    else if (i < 960u)  j = (i - 896u)  << 3;      // st6
    else if (i < 992u)  j = (i - 960u)  << 4;      // st5
    else if (i < 1008u) j = (i - 992u)  << 5;      // st4
    else if (i < 1016u) j = (i - 1008u) << 6;      // st3
    else if (i < 1020u) j = (i - 1016u) << 7;      // st2
    else if (i < 1022u) j = (i - 1020u) << 8;      // st1
    else                j = 0u;                    // st0 (w=1) + pad
    const uint32_t w = powmod_dev(WINV, j << 10);
    g_TWp[i] = make_uint2(w, (uint32_t)((((uint64_t)w) << 32) / PRIME));
  }
}

// ---------------- elementwise: t, f + bucket count ----------------
__global__ __launch_bounds__(1024) void k_elemA(
    const uint32_t* __restrict__ wl, const uint32_t* __restrict__ wr,
    const uint32_t* __restrict__ wo, const uint32_t* __restrict__ w4,
    const uint32_t* __restrict__ ql, const uint32_t* __restrict__ x1,
    const uint32_t* __restrict__ x2, const uint32_t* __restrict__ x3,
    const uint32_t* __restrict__ x4, const uint32_t* __restrict__ zeta_p,
    uint32_t* __restrict__ o32)
{
  __shared__ uint32_t hcnt[2048];
  const int t = threadIdx.x;
  hcnt[t] = 0u; hcnt[t + 1024] = 0u;
  __syncthreads();

  const uint32_t zeta = zeta_p[0];
  const uint32_t zc2 = mulmod(zeta, zeta), zc3 = mulmod(zc2, zeta);
  const uint32_t i0 = (uint32_t)blockIdx.x * 4096u + (uint32_t)t * 4u;

  uint4 vt1 = *(const uint4*)(x1 + i0);
  uint4 vt2 = *(const uint4*)(x2 + i0);
  uint4 vt3 = *(const uint4*)(x3 + i0);
  uint4 vt4 = *(const uint4*)(x4 + i0);
  uint4 vwl = *(const uint4*)(wl + i0);
  uint4 vwr = *(const uint4*)(wr + i0);
  uint4 vwo = *(const uint4*)(wo + i0);
  uint4 vw4 = *(const uint4*)(w4 + i0);
  uint4 vql = *(const uint4*)(ql + i0);

  uint32_t T1[4] = {vt1.x, vt1.y, vt1.z, vt1.w};
  uint32_t T2[4] = {vt2.x, vt2.y, vt2.z, vt2.w};
  uint32_t T3[4] = {vt3.x, vt3.y, vt3.z, vt3.w};
  uint32_t T4[4] = {vt4.x, vt4.y, vt4.z, vt4.w};
  uint32_t L1[4] = {vwl.x, vwl.y, vwl.z, vwl.w};
  uint32_t L2[4] = {vwr.x, vwr.y, vwr.z, vwr.w};
  uint32_t L3[4] = {vwo.x, vwo.y, vwo.z, vwo.w};
  uint32_t L4[4] = {vw4.x, vw4.y, vw4.z, vw4.w};
  uint32_t QL[4] = {vql.x, vql.y, vql.z, vql.w};

  uint32_t tv[4], fv[4];
  #pragma unroll
  for (int k = 0; k < 4; ++k){
    uint32_t tt = addmod(addmod(T1[k], mulmod(zeta, T2[k])),
                         addmod(mulmod(zc2, T3[k]), mulmod(zc3, T4[k])));
    uint32_t qq = addmod(addmod(L1[k], mulmod(zeta, L2[k])),
                         addmod(mulmod(zc2, L3[k]), mulmod(zc3, L4[k])));
    tv[k] = tt; fv[k] = (QL[k] == 1u) ? qq : tt;
  }
  uint4 o;
  o.x = tv[0]; o.y = tv[1]; o.z = tv[2]; o.w = tv[3];
  *(uint4*)(o32 + 5u*NN + i0) = o;                      // T -> slot5
  o.x = fv[0]; o.y = fv[1]; o.z = fv[2]; o.w = fv[3];
  *(uint4*)(o32 + 4u*NN + i0) = o;                      // F -> slot4

  #pragma unroll
  for (int k = 0; k < 4; ++k){ atomicAdd(&hcnt[fv[k] >> 20], 1u);
                               atomicAdd(&hcnt[tv[k] >> 20], 1u); }
  __syncthreads();
  uint32_t c0 = hcnt[t];          if (c0) atomicAdd(&g_bcnt[t], c0);
  uint32_t c1 = hcnt[t + 1024];   if (c1) atomicAdd(&g_bcnt[t + 1024], c1);
}

// ---------------- bucket offset scan (1 block) ----------------
__global__ __launch_bounds__(1024) void k_bscan(){
  __shared__ uint32_t SA[2048], SB[2048];
  const int t = threadIdx.x;
  SA[t] = g_bcnt[t];
  SA[t + 1024] = g_bcnt[t + 1024];
  __syncthreads();
  uint32_t* sp = SA; uint32_t* dp = SB;
  for (int off = 1; off < 2048; off <<= 1){
    for (int i = t; i < 2048; i += 1024)
      dp[i] = (i >= off) ? (sp[i - off] + sp[i]) : sp[i];
    uint32_t* tmp = sp; sp = dp; dp = tmp;
    __syncthreads();
  }
  uint32_t e0 = t ? sp[t - 1] : 0u;
  uint32_t e1 = sp[t + 1023];
  g_boff[t] = e0;         g_bcur[t] = e0;
  g_boff[t + 1024] = e1;  g_bcur[t + 1024] = e1;
}

// ---------------- aggregated scatter: block-local counting sort, then
// coalesced-run write-out into final sorted-array position ----------------
__global__ __launch_bounds__(1024) void k_scat2(uint32_t* __restrict__ o32){
  __shared__ uint32_t sorted[8192];
  __shared__ uint32_t hist[2048];
  __shared__ uint32_t SA[2048];
  __shared__ uint32_t wsum[16];
  __shared__ uint32_t gbase[2048];
  const int t = threadIdx.x;
  const uint32_t base = blockIdx.x * 8192u;   // over F|T = o32[4N .. 6N)

  hist[t] = 0u; hist[t + 1024] = 0u;
  __syncthreads();

  uint32_t v[8], rk[8];
  #pragma unroll
  for (int k = 0; k < 8; ++k)
    v[k] = o32[4u*NN + base + (uint32_t)t + (uint32_t)k * 1024u];
  #pragma unroll
  for (int k = 0; k < 8; ++k)
    rk[k] = atomicAdd(&hist[v[k] >> 20], 1u);
  __syncthreads();

  // shfl-based inclusive scan of hist[0..2047] into SA
  const uint32_t lane = (uint32_t)t & 63u, wid = (uint32_t)t >> 6;   // 16 waves
  const uint32_t e0 = hist[2*t], e1 = hist[2*t + 1];
  const uint32_t s = e0 + e1;
  uint32_t scan = s;
  #pragma unroll
  for (int off = 1; off < 64; off <<= 1){
    uint32_t u = __shfl_up(scan, off, 64);
    if (lane >= (uint32_t)off) scan += u;
  }
  if (lane == 63u) wsum[wid] = scan;
  __syncthreads();
  if (t < 64){
    uint32_t u = (t < 16) ? wsum[t] : 0u;
    #pragma unroll
    for (int off = 1; off < 16; off <<= 1){
      uint32_t x2 = __shfl_up(u, off, 64);
      if ((uint32_t)t >= (uint32_t)off) u += x2;
    }
    if (t < 16) wsum[t] = u;
  }
  __syncthreads();
  const uint32_t wbase = wid ? wsum[wid - 1] : 0u;
  const uint32_t incl = wbase + scan;
  SA[2*t]     = incl - e1;
  SA[2*t + 1] = incl;
  __syncthreads();
  uint32_t* sp = SA;

  // reserve global space: one atomic per non-empty bucket per block
  for (int b = t; b < 2048; b += 1024){
    uint32_t c = hist[b];
    if (c) gbase[b] = atomicAdd(&g_bcur[b], c);
  }
  __syncthreads();

  // scatter into bucket-sorted LDS order
  #pragma unroll
  for (int k = 0; k < 8; ++k){
    uint32_t b = v[k] >> 20;
    uint32_t ls = b ? sp[b - 1] : 0u;
    sorted[ls + rk[k]] = v[k];
  }
  __syncthreads();

  // linear write-out: consecutive i in same bucket -> consecutive global dst
  for (int i = t; i < 8192; i += 1024){
    uint32_t vv = sorted[i];
    uint32_t b = vv >> 20;
    uint32_t ls = b ? sp[b - 1] : 0u;
    o32[6u*NN + gbase[b] + (uint32_t)i - ls] = vv;
  }
}

// ---------------- per-bucket sort: MSD digit (bits [10,20)) counting sort
// + tiny per-digit insertion sort. Values in a bucket share the top 11 bits. --
__global__ __launch_bounds__(256) void k_bsort(uint32_t* __restrict__ o32){
  __shared__ uint32_t sorted[2048];
  __shared__ uint32_t SA[1024], SB[1024];
  __shared__ uint32_t wsum[4];
  const int b = blockIdx.x, t = threadIdx.x;
  uint32_t n = g_bcnt[b]; if (n > 2048u) n = 2048u;
  const uint32_t off = g_boff[b];

  for (int i = t; i < 1024; i += 256) SA[i] = 0u;
  __syncthreads();

  uint32_t v[8], rk[8];
  #pragma unroll
  for (int k = 0; k < 8; ++k){
    const uint32_t i = (uint32_t)t + (uint32_t)k * 256u;
    if (i < n){
      v[k] = o32[6u*NN + off + i];
      rk[k] = atomicAdd(&SA[(v[k] >> 10) & 1023u], 1u);
    }
  }
  __syncthreads();

  // shfl-based inclusive scan of SA[0..1023] into SB
  const uint32_t lane = (uint32_t)t & 63u, wid = (uint32_t)t >> 6;   // 4 waves
  const uint32_t h0 = SA[4*t], h1 = SA[4*t + 1], h2 = SA[4*t + 2], h3 = SA[4*t + 3];
  const uint32_t s = h0 + h1 + h2 + h3;
  uint32_t scan = s;
  #pragma unroll
  for (int o = 1; o < 64; o <<= 1){
    uint32_t u = __shfl_up(scan, o, 64);
    if (lane >= (uint32_t)o) scan += u;
  }
  if (lane == 63u) wsum[wid] = scan;
  __syncthreads();
  if (t < 64){
    uint32_t u = (t < 4) ? wsum[t] : 0u;
    #pragma unroll
    for (int o = 1; o < 4; o <<= 1){
      uint32_t x2 = __shfl_up(u, o, 64);
      if ((uint32_t)t >= (uint32_t)o) u += x2;
    }
    if (t < 4) wsum[t] = u;
  }
  __syncthreads();
  const uint32_t wbase = wid ? wsum[wid - 1] : 0u;
  const uint32_t incl = wbase + scan;
  SB[4*t + 3] = incl;
  SB[4*t + 2] = incl - h3;
  SB[4*t + 1] = incl - h3 - h2;
  SB[4*t + 0] = incl - h3 - h2 - h1;
  __syncthreads();
  uint32_t* sp = SB;

  // scatter by digit
  #pragma unroll
  for (int k = 0; k < 8; ++k){
    const uint32_t i = (uint32_t)t + (uint32_t)k * 256u;
    if (i < n){
      const uint32_t d = (v[k] >> 10) & 1023u;
      const uint32_t s2 = d ? sp[d - 1] : 0u;
      sorted[s2 + rk[k]] = v[k];
    }
  }
  __syncthreads();

  // finish each digit run (mean length <= 2, max ~12) with insertion sort
  for (int d = t; d < 1024; d += 256){
    const uint32_t s2 = d ? sp[d - 1] : 0u;
    const uint32_t e = sp[d];
    for (uint32_t i = s2 + 1; i < e; ++i){
      const uint32_t key = sorted[i];
      uint32_t j = i;
      while (j > s2 && sorted[j - 1] > key){ sorted[j] = sorted[j - 1]; --j; }
      sorted[j] = key;
    }
  }
  __syncthreads();

  for (uint32_t i = (uint32_t)t; i < n; i += 256u) o32[6u*NN + off + i] = sorted[i];
}

// ---------------- ratios + block-local multiplicative scan (8 elems/thread) --
__global__ __launch_bounds__(256) void k_ratio(
    const uint32_t* __restrict__ wl, const uint32_t* __restrict__ wr,
    const uint32_t* __restrict__ wo, const uint32_t* __restrict__ w4,
    const uint32_t* __restrict__ sl, const uint32_t* __restrict__ sr,
    const uint32_t* __restrict__ so, const uint32_t* __restrict__ s4,
    const uint32_t* __restrict__ beta_p, const uint32_t* __restrict__ gamma_p,
    const uint32_t* __restrict__ delta_p, const uint32_t* __restrict__ eps_p,
    uint32_t* __restrict__ o32)
{
  __shared__ uint32_t SA[256], SB[256];
  const int blk = blockIdx.x, t = threadIdx.x;         // 1024 blocks: 512 z | 512 z2
  const int second = blk >> 9;
  const uint32_t base = ((uint32_t)(blk & 511) << 11) + ((uint32_t)t << 3);
  uint32_t num[8], den[8];
  if (!second){
    const uint32_t beta = beta_p[0], gamma = gamma_p[0];
    #pragma unroll
    for (int k = 0; k < 8; ++k){
      uint32_t i = base + (uint32_t)k;
      uint32_t e = (NN - i) & (NN - 1u);               // W^i = WINV^((N-i) mod N)
      uint32_t om = mulmod(g_U[e & 1023u], g_V[e >> 10]);
      uint32_t bo = mulmod(beta, om);
      uint32_t n = addmod3(wl[i], bo, gamma);
      n = mulmod(n, addmod3(wr[i], mulmod(7u,  bo), gamma));
      n = mulmod(n, addmod3(wo[i], mulmod(13u, bo), gamma));
      n = mulmod(n, addmod3(w4[i], mulmod(17u, bo), gamma));
      uint32_t d = addmod3(wl[i], mulmod(beta, sl[i]), gamma);
      d = mulmod(d, addmod3(wr[i], mulmod(beta, sr[i]), gamma));
      d = mulmod(d, addmod3(wo[i], mulmod(beta, so[i]), gamma));
      d = mulmod(d, addmod3(w4[i], mulmod(beta, s4[i]), gamma));
      num[k] = n; den[k] = d;
    }
  } else {
    const uint32_t del = delta_p[0], ep = eps_p[0];
    const uint32_t opd = addmod(1u, del), ep1d = mulmod(ep, opd);
    #pragma unroll
    for (int k = 0; k < 8; ++k){
      uint32_t i = base + (uint32_t)k;
      uint32_t fi = o32[4u*NN + i], ti = o32[5u*NN + i];
      uint32_t tn = o32[5u*NN + ((i + 1u) & (NN - 1u))];
      uint32_t h1  = o32[6u*NN + 2u*i];
      uint32_t h2  = o32[6u*NN + 2u*i + 1u];
      uint32_t h1n = o32[6u*NN + ((2u*i + 2u) & (2u*NN - 1u))];
      uint32_t h2n = o32[6u*NN + ((2u*i + 3u) & (2u*NN - 1u))];
      uint32_t n = mulmod(opd, addmod(ep, fi));
      n = mulmod(n, addmod3(ep1d, ti, mulmod(del, tn)));
      uint32_t d = mulmod(addmod3(ep1d, h1, mulmod(del, h1n)),
                          addmod3(ep1d, h2, mulmod(del, h2n)));
      num[k] = n; den[k] = d;
    }
  }
  bool ok = true;
  #pragma unroll
  for (int k = 0; k < 8; ++k) ok = ok && (den[k] != 0u);
  uint32_t r[8];
  if (ok){
    uint32_t pp[8];
    pp[0] = den[0];
    #pragma unroll
    for (int k = 1; k < 8; ++k) pp[k] = mulmod(pp[k-1], den[k]);
    uint32_t iv = powmod_dev(pp[7], PRIME - 2u);
    #pragma unroll
    for (int k = 7; k >= 1; --k){
      r[k] = mulmod(num[k], mulmod(iv, pp[k-1]));
      iv = mulmod(iv, den[k]);
    }
    r[0] = mulmod(num[0], iv);
  } else {
    #pragma unroll
    for (int k = 0; k < 8; ++k) r[k] = mulmod(num[k], powmod_dev(den[k], PRIME - 2u));
  }
  uint32_t tp = r[0];
  #pragma unroll
  for (int k = 1; k < 8; ++k) tp = mulmod(tp, r[k]);
  SA[t] = tp; __syncthreads();
  uint32_t* sp = SA; uint32_t* dp = SB;
  for (int off = 1; off < 256; off <<= 1){
    dp[t] = (t >= off) ? mulmod(sp[t - off], sp[t]) : sp[t];
    uint32_t* tmp = sp; sp = dp; dp = tmp;
    __syncthreads();
  }
  if (t == 255) g_btot[blk] = sp[255];
  uint32_t run = t ? sp[t - 1] : 1u;
  const uint32_t zo = 8u*NN + ((uint32_t)second << 20) + base;
  #pragma unroll
  for (int k = 0; k < 8; ++k){
    o32[zo + (uint32_t)k] = run;
    run = mulmod(run, r[k]);
  }
}

__global__ __launch_bounds__(512) void k_btscan(){
  __shared__ uint32_t SA[512], SB[512];
  const int a = blockIdx.x, t = threadIdx.x;
  SA[t] = g_btot[a * 512 + t];
  __syncthreads();
  uint32_t* sp = SA; uint32_t* dp = SB;
  for (int off = 1; off < 512; off <<= 1){
    dp[t] = (t >= off) ? mulmod(sp[t - off], sp[t]) : sp[t];
    uint32_t* tmp = sp; sp = dp; dp = tmp;
    __syncthreads();
  }
  g_bpre[a * 512 + t] = t ? sp[t - 1] : 1u;
}

__global__ __launch_bounds__(256) void k_apply(uint32_t* __restrict__ o32){
  const uint32_t g = blockIdx.x * 256u + threadIdx.x;   // [0, 2N/4)
  const uint32_t base = g << 2;
  const uint32_t m = g_bpre[base >> 11];
  uint4* zz = (uint4*)(o32 + 8u*NN);
  uint4 v = zz[g];
  v.x = mulmod(v.x, m); v.y = mulmod(v.y, m); v.z = mulmod(v.z, m); v.w = mulmod(v.w, m);
  zz[g] = v;
}

// ================= four-step INTT (register-resident, Shoup, stage-major LDS twiddles) =================
struct Desc  { const uint32_t* p; uint32_t stride; uint32_t off; };
struct Descs { Desc d[10]; };
struct Map   { int g[10]; };

#define SWZ(i, c) (((i) << 4) + ((c) ^ (((i) >> 1) & 15)))

// 1024-pt GS-DIF NTT on registers: lane l, reg r hold position p = l + 64r.
// Stages st=9..6: same-lane register pairs. Stages st=5..0: shfl_xor partners.
// Twiddles from the stage-major LDS table (all reads lane-contiguous -> no
// bank conflicts). On exit position p holds X[rev10(p)].
__device__ __forceinline__ void ntt1024_reg(uint32_t x[16], int l,
                                            const uint2* __restrict__ sTW){
  #pragma unroll
  for (int st = 9; st >= 6; --st){
    const int bb = 1 << (st - 6);
    const int base = (st == 9) ? 0 : (st == 8) ? 512 : (st == 7) ? 768 : 896;
    #pragma unroll
    for (int r = 0; r < 16; ++r){
      if ((r & bb) == 0){
        const int r2 = r | bb;
        const uint32_t u = x[r], v = x[r2];
        const uint2 wv = sTW[base + ((r & (bb - 1)) << 6) + l];
        x[r]  = addmod(u, v);
        x[r2] = shoup_mul(submod(u, v), wv.x, wv.y);
      }
    }
  }
  #pragma unroll
  for (int st = 5; st >= 0; --st){
    const int h = 1 << st;
    const int base = (st == 5) ? 960 : (st == 4) ? 992 : (st == 3) ? 1008
                   : (st == 2) ? 1016 : (st == 1) ? 1020 : 1022;
    const uint2 wv = sTW[base + (l & (h - 1))];
    const bool hi = (l & h) != 0;
    #pragma unroll
    for (int r = 0; r < 16; ++r){
      const uint32_t y = __shfl_xor(x[r], h, 64);
      const uint32_t a = addmod(x[r], y);
      const uint32_t b = shoup_mul(submod(y, x[r]), wv.x, wv.y);
      x[r] = hi ? b : a;
    }
  }
}

__global__ __launch_bounds__(1024, 8) void k_intt1(Descs ds, uint32_t* __restrict__ mid){
  __shared__ uint32_t tile[16384];
  __shared__ uint2 sTW[1024];
  const int arr = blockIdx.x >> 6;
  const int c0 = (blockIdx.x & 63) << 4;
  const Desc de = ds.d[arr];
  const int t = threadIdx.x;
  sTW[t] = g_TWp[t];
  if (de.stride == 1u){
    #pragma unroll
    for (int it = 0; it < 4; ++it){
      const int row = (it << 8) + (t >> 2);
      const int cb = (t & 3) << 2;
      uint4 v = *(const uint4*)(de.p + (size_t)row * 1024u + (uint32_t)(c0 + cb));
      tile[SWZ(row, cb + 0)] = v.x; tile[SWZ(row, cb + 1)] = v.y;
      tile[SWZ(row, cb + 2)] = v.z; tile[SWZ(row, cb + 3)] = v.w;
    }
  } else {                                   // stride 2 (h1/h2 from S)
    #pragma unroll
    for (int it = 0; it < 4; ++it){
      const int row = (it << 8) + (t >> 2);
      const int cb = (t & 3) << 2;
      const size_t b0 = 2u * ((size_t)row * 1024u + (uint32_t)(c0 + cb));
      uint4 a0 = *(const uint4*)(de.p + b0);
      uint4 a1 = *(const uint4*)(de.p + b0 + 4u);
      if (de.off == 0u){
        tile[SWZ(row, cb + 0)] = a0.x; tile[SWZ(row, cb + 1)] = a0.z;
        tile[SWZ(row, cb + 2)] = a1.x; tile[SWZ(row, cb + 3)] = a1.z;
      } else {
        tile[SWZ(row, cb + 0)] = a0.y; tile[SWZ(row, cb + 1)] = a0.w;
        tile[SWZ(row, cb + 2)] = a1.y; tile[SWZ(row, cb + 3)] = a1.w;
      }
    }
  }
  __syncthreads();
  const int w = t >> 6, l = t & 63;
  uint32_t x[16];
  #pragma unroll
  for (int r = 0; r < 16; ++r) x[r] = tile[SWZ(l + (r << 6), w)];
  ntt1024_reg(x, l, sTW);
  // inter-pass twiddle (N^-1 folded into U2): position p holds X[rev10(p)].
  // U2 gathers go to global (8KB table, L1-resident); V[h] for h<512 sits in
  // sTW's st9 region; V[512+j] = P - V[j] with shoup companion ~ws (exact).
  const uint32_t i1g = (uint32_t)(c0 + w);
  const uint32_t rl = __brev((uint32_t)l) >> 26;        // rev6(l)
  #pragma unroll
  for (int r = 0; r < 16; ++r){
    const uint32_t rr = __brev((uint32_t)r) >> 28;      // rev4(r)
    const uint32_t j1 = (rl << 4) | rr;
    const uint32_t e = j1 * i1g;                        // < 2^20
    const uint2 wa = g_U2p[e & 1023u];
    const uint32_t hv = e >> 10;
    const uint2 wb = sTW[hv & 511u];
    uint32_t wbw = wb.x, wbs = wb.y;
    if (hv & 512u){ wbw = PRIME - wbw; wbs = ~wbs; }
    x[r] = shoup_mul(x[r], wa.x, wa.y);
    x[r] = shoup_mul(x[r], wbw, wbs);
  }
  __syncthreads();
  #pragma unroll
  for (int r = 0; r < 16; ++r) tile[SWZ(l + (r << 6), w)] = x[r];
  __syncthreads();
  uint32_t* mo = mid + ((size_t)arr << 20);
  #pragma unroll
  for (int it = 0; it < 4; ++it){
    const int row = (it << 8) + (t >> 2);
    const int cb = (t & 3) << 2;
    uint4 v;
    v.x = tile[SWZ(row, cb + 0)]; v.y = tile[SWZ(row, cb + 1)];
    v.z = tile[SWZ(row, cb + 2)]; v.w = tile[SWZ(row, cb + 3)];
    *(uint4*)(mo + (size_t)row * 1024u + (uint32_t)(c0 + cb)) = v;
  }
}

__global__ __launch_bounds__(1024, 8) void k_intt2(const uint32_t* __restrict__ mid,
                                                   uint32_t* __restrict__ o32,
                                                   const uint32_t* __restrict__ ck,
                                                   Map mp){
  __shared__ uint32_t tile[16384];
  __shared__ uint2 sTW[1024];
  const int arrL = blockIdx.x >> 6;
  const int m0 = (blockIdx.x & 63) << 4;
  const int t = threadIdx.x;
  const int w = t >> 6, l = t & 63;
  const int gidx = mp.g[arrL];
  const uint32_t* mi = mid + ((size_t)arrL << 20);
  const uint32_t p = __brev((uint32_t)(m0 + w)) >> 22;   // physical source row for j1=m0+w
  sTW[t] = g_TWp[t];
  #pragma unroll
  for (int it = 0; it < 4; ++it){
    const int kb = (it << 8) + (l << 2);
    uint4 v = *(const uint4*)(mi + p * 1024u + (uint32_t)kb);
    tile[SWZ(kb + 0, w)] = v.x; tile[SWZ(kb + 1, w)] = v.y;
    tile[SWZ(kb + 2, w)] = v.z; tile[SWZ(kb + 3, w)] = v.w;
  }
  __syncthreads();
  uint32_t x[16];
  #pragma unroll
  for (int r = 0; r < 16; ++r) x[r] = tile[SWZ(l + (r << 6), w)];
  ntt1024_reg(x, l, sTW);
  __syncthreads();
  #pragma unroll
  for (int r = 0; r < 16; ++r) tile[SWZ(l + (r << 6), w)] = x[r];
  __syncthreads();
  unsigned long long acc = 0ull;
  uint32_t* oa = o32 + ((size_t)gidx << 20);
  #pragma unroll
  for (int it = 0; it < 4; ++it){
    const int j2 = (it << 8) + (t >> 2);
    const int rb = (t & 3) << 2;
    const uint32_t q = __brev((uint32_t)j2) >> 22;
    uint4 v;
    v.x = tile[SWZ((int)q, rb + 0)]; v.y = tile[SWZ((int)q, rb + 1)];
    v.z = tile[SWZ((int)q, rb + 2)]; v.w = tile[SWZ((int)q, rb + 3)];
    const uint32_t oi = (uint32_t)j2 * 1024u + (uint32_t)(m0 + rb);
    *(uint4*)(oa + oi) = v;                              // int32 output
    uint4 cv = *(const uint4*)(ck + oi);
    acc += (unsigned long long)mulmod(v.x, cv.x);
    acc += (unsigned long long)mulmod(v.y, cv.y);
    acc += (unsigned long long)mulmod(v.z, cv.z);
    acc += (unsigned long long)mulmod(v.w, cv.w);
  }
  // wave-level reduce, then 16 wave-sums via first wave
  #pragma unroll
  for (int off = 32; off >= 1; off >>= 1) acc += __shfl_down(acc, off, 64);
  __syncthreads();
  unsigned long long* redw = (unsigned long long*)tile;
  if (l == 0) redw[w] = acc;
  __syncthreads();
  if (t < 64){
    unsigned long long s = (t < 16) ? redw[t] : 0ull;
    #pragma unroll
    for (int off = 8; off >= 1; off >>= 1) s += __shfl_down(s, off, 64);
    if (t == 0) atomicAdd(&g_commit[gidx], s);
  }
}

// ================= textbook INTT (fallback when ws too small) =================
__global__ __launch_bounds__(256) void k_brev(const uint32_t* __restrict__ src,
                                              uint32_t stride, uint32_t off,
                                              uint32_t* __restrict__ dst){
  const uint32_t i = blockIdx.x * 256u + threadIdx.x;    // [0, N)
  const uint32_t r = __brev(i) >> 12;                    // bitrev20
  dst[i] = src[(size_t)r * stride + off];
}

__global__ __launch_bounds__(1024) void k_stage09(uint32_t* __restrict__ wk){
  __shared__ uint32_t sm[1024];
  const int t = threadIdx.x;
  const uint32_t gbase = blockIdx.x * 1024u;
  sm[t] = wk[gbase + t];
  __syncthreads();
  for (int s = 0; s <= 9; ++s){
    if (t < 512){
      const int half = 1 << s;
      const int k = t & (half - 1);
      const int i0 = ((t >> s) << (s + 1)) | k;
      const int i1 = i0 + half;
      const uint32_t tw = g_V[(uint32_t)k << (9 - s)];
      const uint32_t u = sm[i0];
      const uint32_t tv = mulmod(sm[i1], tw);
      sm[i0] = addmod(u, tv);
      sm[i1] = submod(u, tv);
    }
    __syncthreads();
  }
  wk[gbase + t] = sm[t];
}

__global__ __launch_bounds__(256) void k_stage(uint32_t* __restrict__ wk, int s){
  const uint32_t q = blockIdx.x * 256u + threadIdx.x;    // [0, N/2)
  const uint32_t half = 1u << s;
  const uint32_t k = q & (half - 1u);
  const uint32_t i0 = ((q >> s) << (s + 1)) | k;
  const uint32_t i1 = i0 + half;
  const uint32_t e = k << (19 - s);
  const uint32_t tw = mulmod(g_U[e & 1023u], g_V[e >> 10]);
  const uint32_t u = wk[i0];
  const uint32_t tv = mulmod(wk[i1], tw);
  wk[i0] = addmod(u, tv);
  wk[i1] = submod(u, tv);
}

__global__ __launch_bounds__(1024) void k_scale_commit(const uint32_t* __restrict__ src,
                                                       uint32_t* dst,
                                                       const uint32_t* __restrict__ ck,
                                                       int cidx){
  __shared__ unsigned long long red[1024];
  const uint32_t i = blockIdx.x * 1024u + threadIdx.x;   // [0, N)
  const uint32_t val = mulmod(src[i], NINV);
  dst[i] = val;                                          // int32 output
  red[threadIdx.x] = (unsigned long long)mulmod(val, ck[i]);
  __syncthreads();
  for (int s = 512; s > 0; s >>= 1){
    if ((int)threadIdx.x < s) red[threadIdx.x] += red[threadIdx.x + s];
    __syncthreads();
  }
  if (threadIdx.x == 0) atomicAdd(&g_commit[cidx], red[0]);
}

__global__ void k_final(uint32_t* __restrict__ out){
  const int i = threadIdx.x;
  if (i < 10) out[(size_t)10 * NN + i] = (uint32_t)(g_commit[i] % (unsigned long long)PRIME);
}

// ---------------- host ----------------
extern "C" void kernel_launch(void* const* d_in, const int* in_sizes, int n_in,
                              void* d_out, int out_size, void* d_ws, size_t ws_size,
                              hipStream_t stream)
{
  const uint32_t* wl   = (const uint32_t*)d_in[0];
  const uint32_t* wr   = (const uint32_t*)d_in[1];
  const uint32_t* wo   = (const uint32_t*)d_in[2];
  const uint32_t* w4   = (const uint32_t*)d_in[3];
  const uint32_t* ql   = (const uint32_t*)d_in[4];
  const uint32_t* t1   = (const uint32_t*)d_in[5];
  const uint32_t* t2   = (const uint32_t*)d_in[6];
  const uint32_t* t3   = (const uint32_t*)d_in[7];
  const uint32_t* t4   = (const uint32_t*)d_in[8];
  const uint32_t* sl   = (const uint32_t*)d_in[9];
  const uint32_t* sr   = (const uint32_t*)d_in[10];
  const uint32_t* so   = (const uint32_t*)d_in[11];
  const uint32_t* s4   = (const uint32_t*)d_in[12];
  const uint32_t* ck   = (const uint32_t*)d_in[13];
  const uint32_t* zeta = (const uint32_t*)d_in[14];
  const uint32_t* beta = (const uint32_t*)d_in[15];
  const uint32_t* gam  = (const uint32_t*)d_in[16];
  const uint32_t* del  = (const uint32_t*)d_in[17];
  const uint32_t* eps  = (const uint32_t*)d_in[18];
  uint32_t* o32 = (uint32_t*)d_out;
  (void)in_sizes; (void)n_in; (void)out_size;

  k_zero  <<<2, 1024, 0, stream>>>();
  k_tables<<<4, 1024, 0, stream>>>();
  k_elemA <<<256, 1024, 0, stream>>>(wl, wr, wo, w4, ql, t1, t2, t3, t4, zeta, o32);
  k_bscan <<<1, 1024, 0, stream>>>();
  k_scat2 <<<256, 1024, 0, stream>>>(o32);
  k_bsort <<<1920, 256, 0, stream>>>(o32);
  k_ratio <<<1024, 256, 0, stream>>>(wl, wr, wo, w4, sl, sr, so, s4, beta, gam, del, eps, o32);
  k_btscan<<<2, 512, 0, stream>>>();
  k_apply <<<2048, 256, 0, stream>>>(o32);

  // unified source descriptors, indexed by output slot
  Desc ds[10];
  ds[0] = { wl,          1u, 0u };
  ds[1] = { wr,          1u, 0u };
  ds[2] = { wo,          1u, 0u };
  ds[3] = { w4,          1u, 0u };
  ds[4] = { o32 + 4u*NN, 1u, 0u };   // f
  ds[5] = { o32 + 5u*NN, 1u, 0u };   // t
  ds[6] = { o32 + 6u*NN, 2u, 0u };   // h1 = S[0::2]
  ds[7] = { o32 + 6u*NN, 2u, 1u };   // h2 = S[1::2]
  ds[8] = { o32 + 8u*NN, 1u, 0u };   // z
  ds[9] = { o32 + 9u*NN, 1u, 0u };   // z2

  const size_t wsWords = ws_size / 4u;
  if (wsWords >= 2ull * NN){
    // four-step fast path; h1,h2 must share a chunk (their dsts overwrite S)
    static const int ord[10] = {6,7, 4,5, 8,9, 0,1, 2,3};
    const int chunk = (wsWords >= 10ull * NN) ? 10 : 2;
    uint32_t* mid = (uint32_t*)d_ws;
    for (int s0 = 0; s0 < 10; s0 += chunk){
      const int cnt = (10 - s0 < chunk) ? (10 - s0) : chunk;
      Descs sub; Map mp;
      for (int a = 0; a < 10; ++a){
        const int g = ord[(a < cnt) ? s0 + a : s0];
        sub.d[a] = ds[g]; mp.g[a] = g;
      }
      k_intt1<<<64 * cnt, 1024, 0, stream>>>(sub, mid);
      k_intt2<<<64 * cnt, 1024, 0, stream>>>(mid, o32, ck, mp);
    }
  } else {
    // textbook fallback entirely inside d_out
    auto run_intt = [&](const Desc& d, uint32_t workSlot, int dstSlot){
      uint32_t* wk = o32 + (size_t)workSlot * NN;
      k_brev   <<<4096, 256, 0, stream>>>(d.p, d.stride, d.off, wk);
      k_stage09<<<1024, 1024, 0, stream>>>(wk);
      for (int s = 10; s < 20; ++s)
        k_stage<<<2048, 256, 0, stream>>>(wk, s);
      k_scale_commit<<<1024, 1024, 0, stream>>>(wk, o32 + (size_t)dstSlot * NN, ck, dstSlot);
    };
    // h1/h2: gather both from S before either output overwrites S
    k_brev<<<4096, 256, 0, stream>>>(ds[6].p, 2u, 0u, o32 + 0u*NN);
    k_brev<<<4096, 256, 0, stream>>>(ds[7].p, 2u, 1u, o32 + 1u*NN);
    {
      uint32_t* wk0 = o32;
      uint32_t* wk1 = o32 + NN;
      k_stage09<<<1024, 1024, 0, stream>>>(wk0);
      for (int s = 10; s < 20; ++s) k_stage<<<2048, 256, 0, stream>>>(wk0, s);
      k_scale_commit<<<1024, 1024, 0, stream>>>(wk0, o32 + 6u*NN, ck, 6);
      k_stage09<<<1024, 1024, 0, stream>>>(wk1);
      for (int s = 10; s < 20; ++s) k_stage<<<2048, 256, 0, stream>>>(wk1, s);
      k_scale_commit<<<1024, 1024, 0, stream>>>(wk1, o32 + 7u*NN, ck, 7);
    }
    run_intt(ds[4], 0u, 4);
    run_intt(ds[5], 1u, 5);
    run_intt(ds[8], 0u, 8);
    run_intt(ds[9], 1u, 9);
    run_intt(ds[0], 0u, 0);
    run_intt(ds[1], 1u, 1);
    run_intt(ds[2], 2u, 2);
    run_intt(ds[3], 3u, 3);
  }
  k_final<<<1, 64, 0, stream>>>(o32);
}